// Round 2
// baseline (172.202 us; speedup 1.0000x reference)
//
#include <hip/hip_runtime.h>
#include <math.h>

#define OUT_DIM 8192
#define C_DIM   512
#define B_DIM   16
#define HW      196
#define KB      14          // K-chunk: 196 = 14*14
#define BS_STRIDE 18        // 14 padded to 18 floats: gcd(18,32)=2 -> 16 bank-pair spread
#define C1_CHUNK 64
#define NCH1    8           // c1 chunks of 64
#define NSLAB   16          // 8 chunks * 2 K-splits

// ---------------------------------------------------------------------------
// K1: recover count-sketch (h, s) from the densified [512][8192] matrices.
// ---------------------------------------------------------------------------
__global__ __launch_bounds__(256) void extract_sketch(
    const float* __restrict__ S1, const float* __restrict__ S2,
    int* __restrict__ h1, float* __restrict__ s1,
    int* __restrict__ h2, float* __restrict__ s2)
{
    int bid = blockIdx.x;
    int row = bid & 511;
    const float* S = (bid < 512) ? S1 : S2;
    int* h = (bid < 512) ? h1 : h2;
    float* s = (bid < 512) ? s1 : s2;

    const float4* p = (const float4*)(S + (size_t)row * OUT_DIM);
    int t = threadIdx.x;
#pragma unroll
    for (int m = 0; m < 8; ++m) {
        int q = t + m * 256;            // float4 index, 2048 per row
        float4 v = p[q];
        int base = q * 4;
        if (v.x != 0.f) { h[row] = base + 0; s[row] = v.x; }
        if (v.y != 0.f) { h[row] = base + 1; s[row] = v.y; }
        if (v.z != 0.f) { h[row] = base + 2; s[row] = v.z; }
        if (v.w != 0.f) { h[row] = base + 3; s[row] = v.w; }
    }
}

// ---------------------------------------------------------------------------
// K2: fused Gram + count-sketch scatter.
// 256 blocks of 512 threads (8 waves -> 2 waves/SIMD at 1 block/CU).
// Block (b, chunk, ks): computes G[b, chunk*64:(chunk+1)*64, 0:512] over
// K-half ks (98 of 196 spatial positions). All 512 x-rows for the K-chunk
// staged in LDS (stride-18 floats); 8x8 register tile per thread; scatter
// into an LDS 8192-bin accumulator ALIASED onto the staging buffer.
// XCD swizzle: bid&7 = XCD; each XCD owns 2 batches -> x stays L2-resident.
// ---------------------------------------------------------------------------
__global__ __launch_bounds__(512, 2) void gram_scatter(
    const float* __restrict__ x,
    const int* __restrict__ h1, const float* __restrict__ s1,
    const int* __restrict__ h2, const float* __restrict__ s2,
    float* __restrict__ partials)
{
    __shared__ float lds[C_DIM * BS_STRIDE];  // 36864 B; bins (32KB) alias after compute

    const int bid  = blockIdx.x;
    const int xcd  = bid & 7;
    const int idx  = bid >> 3;        // 0..31
    const int b    = xcd + 8 * (idx & 1);
    const int rest = idx >> 1;        // 0..15
    const int chunk = rest >> 1;      // 0..7
    const int ks    = rest & 1;       // K-half

    const int t  = threadIdx.x;
    const int tx = t & 63;            // c2 lane: c2 = j*64 + tx
    const int ty = t >> 6;            // 0..7 (wave id): c1 = c1_base + ty*8 + i
    const int c1_base = chunk * C1_CHUNK;

    float acc[8][8];
#pragma unroll
    for (int i = 0; i < 8; ++i)
#pragma unroll
        for (int j = 0; j < 8; ++j) acc[i][j] = 0.f;

    const float* xb = x + (size_t)b * C_DIM * HW;

    for (int kc = ks * 7; kc < ks * 7 + 7; ++kc) {
        const int k0 = kc * KB;
        __syncthreads();              // protect lds reuse across iterations
        // stage 512 rows x 14 floats = 3584 float2; 7 per thread
#pragma unroll
        for (int m = 0; m < 7; ++m) {
            int u = t + m * 512;
            int r = u / 7;
            int q = u - r * 7;
            float2 v = *(const float2*)(xb + r * HW + k0 + q * 2);
            *(float2*)(&lds[r * BS_STRIDE + q * 2]) = v;
        }
        __syncthreads();
#pragma unroll
        for (int kk = 0; kk < 7; ++kk) {
            float2 a2[8], b2[8];
#pragma unroll
            for (int i = 0; i < 8; ++i)   // wave-uniform -> broadcast
                a2[i] = *(const float2*)(&lds[(c1_base + ty * 8 + i) * BS_STRIDE + kk * 2]);
#pragma unroll
            for (int j = 0; j < 8; ++j)   // stride-18 spread across bank pairs
                b2[j] = *(const float2*)(&lds[(j * 64 + tx) * BS_STRIDE + kk * 2]);
#pragma unroll
            for (int i = 0; i < 8; ++i)
#pragma unroll
                for (int j = 0; j < 8; ++j)
                    acc[i][j] += a2[i].x * b2[j].x + a2[i].y * b2[j].y;
        }
    }

    // sketch params for this thread's 64 (c1,c2) pairs
    int   hh1[8], hh2[8];
    float ss1[8], ss2[8];
#pragma unroll
    for (int i = 0; i < 8; ++i) {
        int c1 = c1_base + ty * 8 + i;
        hh1[i] = h1[c1]; ss1[i] = s1[c1];
    }
#pragma unroll
    for (int j = 0; j < 8; ++j) {
        int c2 = j * 64 + tx;
        hh2[j] = h2[c2]; ss2[j] = s2[c2];
    }

    __syncthreads();                  // compute done; safe to repurpose lds as bins
    float* bins = lds;
    for (int m = t; m < OUT_DIM; m += 512) bins[m] = 0.f;
    __syncthreads();
#pragma unroll
    for (int i = 0; i < 8; ++i)
#pragma unroll
        for (int j = 0; j < 8; ++j) {
            int bin = (hh1[i] + hh2[j]) & (OUT_DIM - 1);
            atomicAdd(&bins[bin], acc[i][j] * ss1[i] * ss2[j]);
        }
    __syncthreads();

    const int slab = chunk * 2 + ks;
    float* outp = partials + ((size_t)b * NSLAB + slab) * OUT_DIM;
    for (int m = t; m < OUT_DIM; m += 512) outp[m] = bins[m];
}

// ---------------------------------------------------------------------------
// K3: reduce 16 slabs, *8192, signed sqrt, L2 normalize. One block/batch.
// ---------------------------------------------------------------------------
__global__ __launch_bounds__(256) void finalize(
    const float* __restrict__ partials, float* __restrict__ out)
{
    const int b = blockIdx.x;
    const int t = threadIdx.x;
    float xv[32];
    float ss = 0.f;
#pragma unroll
    for (int m = 0; m < 32; ++m) {
        int k = t + m * 256;
        float y = 0.f;
        for (int c = 0; c < NSLAB; ++c)
            y += partials[((size_t)b * NSLAB + c) * OUT_DIM + k];
        y *= (float)OUT_DIM;
        float sg = (y > 0.f) ? 1.f : ((y < 0.f) ? -1.f : 0.f);
        float v = sg * sqrtf(fabsf(y) + 1e-5f);
        xv[m] = v;
        ss += v * v;
    }
#pragma unroll
    for (int off = 32; off; off >>= 1) ss += __shfl_down(ss, off, 64);
    __shared__ float red[4];
    if ((t & 63) == 0) red[t >> 6] = ss;
    __syncthreads();
    float tot = red[0] + red[1] + red[2] + red[3];
    float nrm = fmaxf(sqrtf(tot), 1e-12f);
    float inv = 1.f / nrm;
#pragma unroll
    for (int m = 0; m < 32; ++m)
        out[(size_t)b * OUT_DIM + t + m * 256] = xv[m] * inv;
}

// ---------------------------------------------------------------------------
extern "C" void kernel_launch(void* const* d_in, const int* in_sizes, int n_in,
                              void* d_out, int out_size, void* d_ws, size_t ws_size,
                              hipStream_t stream) {
    const float* x   = (const float*)d_in[0];
    const float* sk1 = (const float*)d_in[1];
    const float* sk2 = (const float*)d_in[2];

    char* ws = (char*)d_ws;
    int*   h1 = (int*)(ws);
    float* s1 = (float*)(ws + 2048);
    int*   h2 = (int*)(ws + 4096);
    float* s2 = (float*)(ws + 6144);
    float* partials = (float*)(ws + 8192);    // [16][16][8192] f32 = 8.39 MB

    extract_sketch<<<1024, 256, 0, stream>>>(sk1, sk2, h1, s1, h2, s2);
    gram_scatter<<<256, 512, 0, stream>>>(x, h1, s1, h2, s2, partials);
    finalize<<<B_DIM, 256, 0, stream>>>(partials, (float*)d_out);
}

// Round 3
// 130.294 us; speedup vs baseline: 1.3216x; 1.3216x over previous
//
#include <hip/hip_runtime.h>
#include <math.h>

#define OUT_DIM 8192
#define C_DIM   512
#define B_DIM   16
#define HW      196
#define KPAD    224          // 7 chunks of 32
#define LROW    40           // LDS row stride in bf16 elems (80 B): b128 reads ~2-way only

typedef __attribute__((ext_vector_type(8))) short bf16x8;
typedef __attribute__((ext_vector_type(4))) float f32x4;

// ---------------------------------------------------------------------------
// K1 "prep": three sections by blockIdx.
//  [0,1024)    extract count-sketch (h,s) from dense S1/S2
//  [1024,1280) convert x fp32 -> xhi/xlo bf16 (truncation split), K padded to 224
//  [1280,1312) zero accum[16][8192] and ss[16]
// ---------------------------------------------------------------------------
__global__ __launch_bounds__(256) void prep(
    const float* __restrict__ x,
    const float* __restrict__ S1, const float* __restrict__ S2,
    int* __restrict__ h1, float* __restrict__ s1,
    int* __restrict__ h2, float* __restrict__ s2,
    unsigned short* __restrict__ xhi, unsigned short* __restrict__ xlo,
    float* __restrict__ accum, float* __restrict__ ss)
{
    const int bid = blockIdx.x;
    const int t = threadIdx.x;

    if (bid < 1024) {
        int row = bid & 511;
        const float* S = (bid < 512) ? S1 : S2;
        int* h = (bid < 512) ? h1 : h2;
        float* s = (bid < 512) ? s1 : s2;
        const float4* p = (const float4*)(S + (size_t)row * OUT_DIM);
#pragma unroll
        for (int m = 0; m < 8; ++m) {
            int q = t + m * 256;
            float4 v = p[q];
            int base = q * 4;
            if (v.x != 0.f) { h[row] = base + 0; s[row] = v.x; }
            if (v.y != 0.f) { h[row] = base + 1; s[row] = v.y; }
            if (v.z != 0.f) { h[row] = base + 2; s[row] = v.z; }
            if (v.w != 0.f) { h[row] = base + 3; s[row] = v.w; }
        }
    } else if (bid < 1280) {
        // 8192 rows total; 32 rows/block; 8 threads per row, 28 elems each (7*28=196)
        int u = bid - 1024;
        int rowg = u * 32 + (t >> 3);
        int kq = t & 7;
        int k0 = kq * 28;
        unsigned short hb[28], lb[28];
        if (kq < 7) {
            const float* src = x + (size_t)rowg * HW + k0;
#pragma unroll
            for (int q = 0; q < 7; ++q) {
                float4 v = *(const float4*)(src + q * 4);
                float vv[4] = {v.x, v.y, v.z, v.w};
#pragma unroll
                for (int e = 0; e < 4; ++e) {
                    unsigned int ub = __float_as_uint(vv[e]);
                    unsigned short hi = (unsigned short)(ub >> 16);
                    float hif = __uint_as_float(((unsigned int)hi) << 16);
                    float lof = vv[e] - hif;
                    unsigned short lo = (unsigned short)(__float_as_uint(lof) >> 16);
                    hb[q * 4 + e] = hi;
                    lb[q * 4 + e] = lo;
                }
            }
        } else {
#pragma unroll
            for (int e = 0; e < 28; ++e) { hb[e] = 0; lb[e] = 0; }
        }
        unsigned short* dh = xhi + (size_t)rowg * KPAD + k0;
        unsigned short* dl = xlo + (size_t)rowg * KPAD + k0;
#pragma unroll
        for (int q = 0; q < 7; ++q) {
            *(ushort4*)(dh + q * 4) = make_ushort4(hb[q*4], hb[q*4+1], hb[q*4+2], hb[q*4+3]);
            *(ushort4*)(dl + q * 4) = make_ushort4(lb[q*4], lb[q*4+1], lb[q*4+2], lb[q*4+3]);
        }
    } else {
        int z = bid - 1280;   // 0..31, zero 131072 floats
#pragma unroll
        for (int i = 0; i < 16; ++i)
            accum[z * 4096 + t + i * 256] = 0.f;
        if (z == 0 && t < 16) ss[t] = 0.f;
    }
}

// ---------------------------------------------------------------------------
// K2: Gram via MFMA (bf16 hi/lo split) + count-sketch scatter.
// 256 blocks x 256 thr (4 waves). Block: batch b, 128x128 (c1,c2) tile.
// Wave (wr,wc) owns a 64x64 sub-tile: acc[4][4] fragments of 16x16.
// Per K-chunk(32): stage Ahi/Alo/Bhi/Blo [128][40] bf16 in LDS, 48 MFMAs/wave.
// Scatter into LDS bins (aliased on staging), then global atomicAdd to accum.
// XCD swizzle keeps each batch's 16 blocks on one XCD (proven R2: FETCH 3.3MB).
// ---------------------------------------------------------------------------
__global__ __launch_bounds__(256) void gram_mfma(
    const unsigned short* __restrict__ xhi, const unsigned short* __restrict__ xlo,
    const int* __restrict__ h1, const float* __restrict__ s1,
    const int* __restrict__ h2, const float* __restrict__ s2,
    float* __restrict__ accum)
{
    __shared__ __align__(16) unsigned short lds[4 * 128 * LROW];  // 40960 B

    const int bid = blockIdx.x;
    const int xcd = bid & 7;
    const int idx = bid >> 3;           // 0..31
    const int b   = xcd + 8 * (idx & 1);
    const int tile = idx >> 1;          // 0..15
    const int i1 = tile >> 2, i2 = tile & 3;
    const int c1b = i1 * 128, c2b = i2 * 128;

    const int t = threadIdx.x;
    const int l = t & 63, w = t >> 6;
    const int wr = w >> 1, wc = w & 1;  // wave 64x64 sub-tile
    const int lrow = l & 15, lk = l >> 4;

    const size_t xbase = (size_t)b * C_DIM * KPAD;

    f32x4 acc[4][4];
#pragma unroll
    for (int m = 0; m < 4; ++m)
#pragma unroll
        for (int n = 0; n < 4; ++n) acc[m][n] = (f32x4){0.f, 0.f, 0.f, 0.f};

    for (int kc = 0; kc < 7; ++kc) {
        __syncthreads();
        // stage 4 tiles x 128 rows x 32 k (as 4 groups of 8 bf16): 2048 units, 8/thread
#pragma unroll
        for (int m = 0; m < 8; ++m) {
            int u = t + m * 256;
            int ts  = u >> 9;           // 0:Ahi 1:Alo 2:Bhi 3:Blo
            int rem = u & 511;
            int row = rem >> 2;
            int grp = rem & 3;
            int cb = (ts < 2) ? c1b : c2b;
            const unsigned short* sp = (ts & 1) ? xlo : xhi;
            bf16x8 v = *(const bf16x8*)(sp + xbase + (size_t)(cb + row) * KPAD + kc * 32 + grp * 8);
            *(bf16x8*)(lds + ts * (128 * LROW) + row * LROW + grp * 8) = v;
        }
        __syncthreads();

        bf16x8 ah[4], al[4], bh[4], bl[4];
#pragma unroll
        for (int m = 0; m < 4; ++m) {
            int r = wr * 64 + m * 16 + lrow;
            ah[m] = *(const bf16x8*)(lds + 0 * (128 * LROW) + r * LROW + lk * 8);
            al[m] = *(const bf16x8*)(lds + 1 * (128 * LROW) + r * LROW + lk * 8);
        }
#pragma unroll
        for (int n = 0; n < 4; ++n) {
            int r = wc * 64 + n * 16 + lrow;
            bh[n] = *(const bf16x8*)(lds + 2 * (128 * LROW) + r * LROW + lk * 8);
            bl[n] = *(const bf16x8*)(lds + 3 * (128 * LROW) + r * LROW + lk * 8);
        }
#pragma unroll
        for (int m = 0; m < 4; ++m)
#pragma unroll
            for (int n = 0; n < 4; ++n) {
                acc[m][n] = __builtin_amdgcn_mfma_f32_16x16x32_bf16(ah[m], bh[n], acc[m][n], 0, 0, 0);
                acc[m][n] = __builtin_amdgcn_mfma_f32_16x16x32_bf16(ah[m], bl[n], acc[m][n], 0, 0, 0);
                acc[m][n] = __builtin_amdgcn_mfma_f32_16x16x32_bf16(al[m], bh[n], acc[m][n], 0, 0, 0);
            }
    }

    // C/D layout (m89-verified): col = lane&15, row = (lane>>4)*4 + reg
    int   hh1[4][4]; float sv1[4][4];
    int   hh2[4];    float sv2[4];
#pragma unroll
    for (int m = 0; m < 4; ++m)
#pragma unroll
        for (int r = 0; r < 4; ++r) {
            int c1 = c1b + wr * 64 + m * 16 + lk * 4 + r;
            hh1[m][r] = h1[c1]; sv1[m][r] = s1[c1];
        }
#pragma unroll
    for (int n = 0; n < 4; ++n) {
        int c2 = c2b + wc * 64 + n * 16 + lrow;
        hh2[n] = h2[c2]; sv2[n] = s2[c2];
    }

    __syncthreads();                    // all frag reads done; repurpose LDS as bins
    float* bins = (float*)lds;
    for (int mm = t; mm < OUT_DIM; mm += 256) bins[mm] = 0.f;
    __syncthreads();
#pragma unroll
    for (int m = 0; m < 4; ++m)
#pragma unroll
        for (int n = 0; n < 4; ++n)
#pragma unroll
            for (int r = 0; r < 4; ++r) {
                int bin = (hh1[m][r] + hh2[n]) & (OUT_DIM - 1);
                atomicAdd(&bins[bin], acc[m][n][r] * sv1[m][r] * sv2[n]);
            }
    __syncthreads();

    float* ab = accum + (size_t)b * OUT_DIM;
    for (int mm = t; mm < OUT_DIM; mm += 256) atomicAdd(&ab[mm], bins[mm]);
}

// ---------------------------------------------------------------------------
// K3a: per-batch sum of squares (norm^2 = sum |8192*a| + eps), 256 blocks.
// ---------------------------------------------------------------------------
__global__ __launch_bounds__(256) void fin_a(
    const float* __restrict__ accum, float* __restrict__ ss)
{
    const int b = blockIdx.x >> 4, ch = blockIdx.x & 15, t = threadIdx.x;
    float p = 0.f;
#pragma unroll
    for (int i = 0; i < 2; ++i) {
        int k = ch * 512 + t + i * 256;
        float a = accum[(size_t)b * OUT_DIM + k] * (float)OUT_DIM;
        p += fabsf(a) + 1e-5f;          // (sign*sqrt(|a|+eps))^2
    }
#pragma unroll
    for (int off = 32; off; off >>= 1) p += __shfl_down(p, off, 64);
    __shared__ float red[4];
    if ((t & 63) == 0) red[t >> 6] = p;
    __syncthreads();
    if (t == 0) atomicAdd(&ss[b], red[0] + red[1] + red[2] + red[3]);
}

// ---------------------------------------------------------------------------
// K3b: signed sqrt + L2 normalize, 256 blocks.
// ---------------------------------------------------------------------------
__global__ __launch_bounds__(256) void fin_b(
    const float* __restrict__ accum, const float* __restrict__ ss,
    float* __restrict__ out)
{
    const int b = blockIdx.x >> 4, ch = blockIdx.x & 15, t = threadIdx.x;
    float inv = 1.f / fmaxf(sqrtf(ss[b]), 1e-12f);
#pragma unroll
    for (int i = 0; i < 2; ++i) {
        int k = ch * 512 + t + i * 256;
        float a = accum[(size_t)b * OUT_DIM + k] * (float)OUT_DIM;
        float sg = (a > 0.f) ? 1.f : ((a < 0.f) ? -1.f : 0.f);
        out[(size_t)b * OUT_DIM + k] = sg * sqrtf(fabsf(a) + 1e-5f) * inv;
    }
}

// ---------------------------------------------------------------------------
extern "C" void kernel_launch(void* const* d_in, const int* in_sizes, int n_in,
                              void* d_out, int out_size, void* d_ws, size_t ws_size,
                              hipStream_t stream) {
    const float* x   = (const float*)d_in[0];
    const float* sk1 = (const float*)d_in[1];
    const float* sk2 = (const float*)d_in[2];

    char* ws = (char*)d_ws;
    int*   h1 = (int*)(ws);                                  //     0 + 2048
    float* s1 = (float*)(ws + 2048);                         //  2048 + 2048
    int*   h2 = (int*)(ws + 4096);                           //  4096 + 2048
    float* s2 = (float*)(ws + 6144);                         //  6144 + 2048
    float* ss = (float*)(ws + 8192);                         //  8192 + 64 (+pad)
    float* accum = (float*)(ws + 8448);                      //  8448 + 524288
    unsigned short* xhi = (unsigned short*)(ws + 532736);    //  + 3670016
    unsigned short* xlo = (unsigned short*)(ws + 4202752);   //  + 3670016 = 7872768 total

    prep<<<1312, 256, 0, stream>>>(x, sk1, sk2, h1, s1, h2, s2, xhi, xlo, accum, ss);
    gram_mfma<<<256, 256, 0, stream>>>(xhi, xlo, h1, s1, h2, s2, accum);
    fin_a<<<256, 256, 0, stream>>>(accum, ss);
    fin_b<<<256, 256, 0, stream>>>(accum, ss, (float*)d_out);
}

// Round 4
// 121.340 us; speedup vs baseline: 1.4192x; 1.0738x over previous
//
#include <hip/hip_runtime.h>
#include <math.h>

#define OUT_DIM 8192
#define C_DIM   512
#define B_DIM   16
#define HW      196
#define LROW    40            // LDS row stride in bf16 elems (80 B = 5 quads): b128 reads 2-way max
#define PL      (128 * LROW)  // plane size (ushorts)

typedef __attribute__((ext_vector_type(8))) short bf16x8;
typedef __attribute__((ext_vector_type(4))) float f32x4;

// ---------------------------------------------------------------------------
// K1 prep: extract count-sketch (h,s) from dense S1/S2; block 0 zeroes ss.
// ---------------------------------------------------------------------------
__global__ __launch_bounds__(256) void prep(
    const float* __restrict__ S1, const float* __restrict__ S2,
    int* __restrict__ h1, float* __restrict__ s1,
    int* __restrict__ h2, float* __restrict__ s2,
    float* __restrict__ ss)
{
    const int bid = blockIdx.x;
    const int t = threadIdx.x;
    int row = bid & 511;
    const float* S = (bid < 512) ? S1 : S2;
    int* h = (bid < 512) ? h1 : h2;
    float* s = (bid < 512) ? s1 : s2;
    const float4* p = (const float4*)(S + (size_t)row * OUT_DIM);
#pragma unroll
    for (int m = 0; m < 8; ++m) {
        int q = t + m * 256;
        float4 v = p[q];
        int base = q * 4;
        if (v.x != 0.f) { h[row] = base + 0; s[row] = v.x; }
        if (v.y != 0.f) { h[row] = base + 1; s[row] = v.y; }
        if (v.z != 0.f) { h[row] = base + 2; s[row] = v.z; }
        if (v.w != 0.f) { h[row] = base + 3; s[row] = v.w; }
    }
    if (bid == 0 && t < B_DIM) ss[t] = 0.f;
}

// ---------------------------------------------------------------------------
// K2: Gram via MFMA (bf16 hi/lo split, conversion fused into staging) +
// count-sketch scatter into LDS bins -> deterministic per-block partial slab.
// 256 blocks x 512 thr (8 waves = 2/SIMD). Block (b, 128x128 tile).
// Wave grid 2x4: wave sub-tile 64x32 -> acc[4][2] 16x16 frags.
// K loop: 7 chunks of 32 (HW=196, last chunk zero-padded), register
// double-buffer: next chunk's fp32 loads issued before current MFMAs.
// XCD swizzle (proven R2/R3): bid&7 = XCD, 2 batches/XCD stay L2-resident.
// ---------------------------------------------------------------------------
__global__ __launch_bounds__(512) void gram_mfma(
    const float* __restrict__ x,
    const int* __restrict__ h1, const float* __restrict__ s1,
    const int* __restrict__ h2, const float* __restrict__ s2,
    float* __restrict__ partials)
{
    __shared__ __align__(16) unsigned short lds[4 * PL];  // 40960 B; bins alias later

    const int bid = blockIdx.x;
    const int xcd = bid & 7;
    const int idx = bid >> 3;            // 0..31
    const int b   = xcd + 8 * (idx & 1);
    const int tile = idx >> 1;           // 0..15
    const int c1b = (tile >> 2) * 128, c2b = (tile & 3) * 128;

    const int t = threadIdx.x;
    const int l = t & 63, w = t >> 6;
    const int wr = w >> 2, wc = w & 3;   // 2x4 wave grid: 64x32 per wave
    const int lrow = l & 15, lk = l >> 4;

    const float* xb = x + (size_t)b * C_DIM * HW;

    // staging role of this thread: m=0 -> A-plane unit, m=1 -> B-plane unit
    const int row0 = t >> 2, grp0 = t & 3;           // row 0..127, grp 0..3 (8 floats)
    const float* srcA = xb + (size_t)(c1b + row0) * HW + grp0 * 8;
    const float* srcB = xb + (size_t)(c2b + row0) * HW + grp0 * 8;

    f32x4 acc[4][2];
#pragma unroll
    for (int m = 0; m < 4; ++m)
#pragma unroll
        for (int n = 0; n < 2; ++n) acc[m][n] = (f32x4){0.f, 0.f, 0.f, 0.f};

    float4 a0, a1, b0, b1;               // prefetch regs (8 floats per plane)
    const float4 z4 = make_float4(0.f, 0.f, 0.f, 0.f);

    // prefetch chunk 0 (k 0..31, all valid)
    a0 = *(const float4*)(srcA);     a1 = *(const float4*)(srcA + 4);
    b0 = *(const float4*)(srcB);     b1 = *(const float4*)(srcB + 4);

#pragma unroll
    for (int kc = 0; kc < 7; ++kc) {
        __syncthreads();                 // previous chunk's frag reads done
        // convert current prefetch -> hi/lo bf16, store to LDS
        {
            float va[8] = {a0.x, a0.y, a0.z, a0.w, a1.x, a1.y, a1.z, a1.w};
            float vb[8] = {b0.x, b0.y, b0.z, b0.w, b1.x, b1.y, b1.z, b1.w};
            bf16x8 ahv, alv, bhv, blv;
#pragma unroll
            for (int e = 0; e < 8; ++e) {
                unsigned int ua = __float_as_uint(va[e]);
                float haf = __uint_as_float(ua & 0xFFFF0000u);
                ahv[e] = (short)(ua >> 16);
                alv[e] = (short)(__float_as_uint(va[e] - haf) >> 16);
                unsigned int ub = __float_as_uint(vb[e]);
                float hbf = __uint_as_float(ub & 0xFFFF0000u);
                bhv[e] = (short)(ub >> 16);
                blv[e] = (short)(__float_as_uint(vb[e] - hbf) >> 16);
            }
            unsigned short* dst = lds + row0 * LROW + grp0 * 8;
            *(bf16x8*)(dst + 0 * PL) = ahv;
            *(bf16x8*)(dst + 1 * PL) = alv;
            *(bf16x8*)(dst + 2 * PL) = bhv;
            *(bf16x8*)(dst + 3 * PL) = blv;
        }
        __syncthreads();
        // issue next chunk's global loads (latency hides under MFMAs below)
        if (kc < 6) {
            const int kn = (kc + 1) * 32;
            if (kc + 1 < 6) {
                a0 = *(const float4*)(srcA + kn); a1 = *(const float4*)(srcA + kn + 4);
                b0 = *(const float4*)(srcB + kn); b1 = *(const float4*)(srcB + kn + 4);
            } else {                      // chunk 6: k 192..223, valid only 192..195
                a1 = z4; b1 = z4;
                a0 = (grp0 == 0) ? *(const float4*)(srcA + 192) : z4;
                b0 = (grp0 == 0) ? *(const float4*)(srcB + 192) : z4;
            }
        }
        // frag reads + 24 MFMAs
        bf16x8 ah[4], al[4], bh[2], bl[2];
#pragma unroll
        for (int m = 0; m < 4; ++m) {
            int r = wr * 64 + m * 16 + lrow;
            ah[m] = *(const bf16x8*)(lds + 0 * PL + r * LROW + lk * 8);
            al[m] = *(const bf16x8*)(lds + 1 * PL + r * LROW + lk * 8);
        }
#pragma unroll
        for (int n = 0; n < 2; ++n) {
            int r = wc * 32 + n * 16 + lrow;
            bh[n] = *(const bf16x8*)(lds + 2 * PL + r * LROW + lk * 8);
            bl[n] = *(const bf16x8*)(lds + 3 * PL + r * LROW + lk * 8);
        }
#pragma unroll
        for (int m = 0; m < 4; ++m)
#pragma unroll
            for (int n = 0; n < 2; ++n) {
                acc[m][n] = __builtin_amdgcn_mfma_f32_16x16x32_bf16(ah[m], bh[n], acc[m][n], 0, 0, 0);
                acc[m][n] = __builtin_amdgcn_mfma_f32_16x16x32_bf16(ah[m], bl[n], acc[m][n], 0, 0, 0);
                acc[m][n] = __builtin_amdgcn_mfma_f32_16x16x32_bf16(al[m], bh[n], acc[m][n], 0, 0, 0);
            }
    }

    // sketch params; C/D layout (R3-verified): col=lane&15 -> c2, row=(lane>>4)*4+r -> c1
    int   hh1[4][4]; float sv1[4][4];
    int   hh2[2];    float sv2[2];
#pragma unroll
    for (int m = 0; m < 4; ++m)
#pragma unroll
        for (int r = 0; r < 4; ++r) {
            int c1 = c1b + wr * 64 + m * 16 + lk * 4 + r;
            hh1[m][r] = h1[c1]; sv1[m][r] = s1[c1];
        }
#pragma unroll
    for (int n = 0; n < 2; ++n) {
        int c2 = c2b + wc * 32 + n * 16 + lrow;
        hh2[n] = h2[c2]; sv2[n] = s2[c2];
    }

    __syncthreads();                     // frag reads done; repurpose LDS as bins
    float* bins = (float*)lds;
    for (int mm = t; mm < OUT_DIM; mm += 512) bins[mm] = 0.f;
    __syncthreads();
#pragma unroll
    for (int m = 0; m < 4; ++m)
#pragma unroll
        for (int n = 0; n < 2; ++n)
#pragma unroll
            for (int r = 0; r < 4; ++r) {
                int bin = (hh1[m][r] + hh2[n]) & (OUT_DIM - 1);
                atomicAdd(&bins[bin], acc[m][n][r] * sv1[m][r] * sv2[n]);
            }
    __syncthreads();

    // deterministic per-block slab (no global atomics)
    float* outp = partials + (size_t)(b * 16 + tile) * OUT_DIM;
    for (int mm = t; mm < OUT_DIM; mm += 512) outp[mm] = bins[mm];
}

// ---------------------------------------------------------------------------
// K3a: reduce 16 slabs -> signed-sqrt values written in-place into slab 0;
// per-batch sum-of-squares via one atomicAdd per block into ss[b].
// ---------------------------------------------------------------------------
__global__ __launch_bounds__(256) void fin_a(
    float* __restrict__ partials, float* __restrict__ ss)
{
    const int b = blockIdx.x >> 4, ch = blockIdx.x & 15, t = threadIdx.x;
    float sq = 0.f;
    float vals[2];
    int ks[2];
#pragma unroll
    for (int i = 0; i < 2; ++i) {
        int k = ch * 512 + i * 256 + t;
        ks[i] = k;
        float a = 0.f;
#pragma unroll
        for (int tile = 0; tile < 16; ++tile)
            a += partials[(size_t)(b * 16 + tile) * OUT_DIM + k];
        a *= (float)OUT_DIM;
        float sg = (a > 0.f) ? 1.f : ((a < 0.f) ? -1.f : 0.f);
        vals[i] = sg * sqrtf(fabsf(a) + 1e-5f);
        sq += fabsf(a) + 1e-5f;          // = vals[i]^2
    }
#pragma unroll
    for (int off = 32; off; off >>= 1) sq += __shfl_down(sq, off, 64);
    __shared__ float red[4];
    if ((t & 63) == 0) red[t >> 6] = sq;
    __syncthreads();
    if (t == 0) atomicAdd(&ss[b], red[0] + red[1] + red[2] + red[3]);
#pragma unroll
    for (int i = 0; i < 2; ++i)
        partials[(size_t)(b * 16) * OUT_DIM + ks[i]] = vals[i];
}

// ---------------------------------------------------------------------------
// K3b: L2 normalize.
// ---------------------------------------------------------------------------
__global__ __launch_bounds__(256) void fin_b(
    const float* __restrict__ partials, const float* __restrict__ ss,
    float* __restrict__ out)
{
    const int b = blockIdx.x >> 4, ch = blockIdx.x & 15, t = threadIdx.x;
    float inv = 1.f / fmaxf(sqrtf(ss[b]), 1e-12f);
#pragma unroll
    for (int i = 0; i < 2; ++i) {
        int k = ch * 512 + i * 256 + t;
        out[(size_t)b * OUT_DIM + k] = partials[(size_t)(b * 16) * OUT_DIM + k] * inv;
    }
}

// ---------------------------------------------------------------------------
extern "C" void kernel_launch(void* const* d_in, const int* in_sizes, int n_in,
                              void* d_out, int out_size, void* d_ws, size_t ws_size,
                              hipStream_t stream) {
    const float* x   = (const float*)d_in[0];
    const float* sk1 = (const float*)d_in[1];
    const float* sk2 = (const float*)d_in[2];

    char* ws = (char*)d_ws;
    int*   h1 = (int*)(ws);                        //    0 + 2048
    float* s1 = (float*)(ws + 2048);               // 2048 + 2048
    int*   h2 = (int*)(ws + 4096);                 // 4096 + 2048
    float* s2 = (float*)(ws + 6144);               // 6144 + 2048
    float* ss = (float*)(ws + 8192);               // 8192 + 256
    float* partials = (float*)(ws + 8448);         // [256][8192] f32 = 8.39 MB

    prep<<<1024, 256, 0, stream>>>(sk1, sk2, h1, s1, h2, s2, ss);
    gram_mfma<<<256, 512, 0, stream>>>(x, h1, s1, h2, s2, partials);
    fin_a<<<256, 256, 0, stream>>>(partials, ss);
    fin_b<<<256, 256, 0, stream>>>(partials, ss, (float*)d_out);
}

// Round 5
// 121.133 us; speedup vs baseline: 1.4216x; 1.0017x over previous
//
#include <hip/hip_runtime.h>
#include <math.h>

#define OUT_DIM 8192
#define C_DIM   512
#define B_DIM   16
#define HW      196

typedef __attribute__((ext_vector_type(8))) short bf16x8;
typedef __attribute__((ext_vector_type(4))) float f32x4;

// Packed fragment-native layout, per plane (hi or lo):
//   idx(b, rb, kb, lk, r, e) = (((b*32 + rb)*7 + kb)*4 + lk)*128 + r*8 + e
// where rb = row/16 (0..31), kb = k/32 (0..6), lk = (k/8)&3, r = row&15, e = k&7.
// A wave's 16x32 fragment at (rb,kb) = contiguous 1KB; lane l reads 16B at l*16.

// ---------------------------------------------------------------------------
// K1 prep: [0,1024) sketch extraction; [1024,1536) pack x -> fragment layout.
// ---------------------------------------------------------------------------
__global__ __launch_bounds__(256) void prep(
    const float* __restrict__ x,
    const float* __restrict__ S1, const float* __restrict__ S2,
    int* __restrict__ h1, float* __restrict__ s1,
    int* __restrict__ h2, float* __restrict__ s2,
    unsigned short* __restrict__ PH, unsigned short* __restrict__ PLo,
    float* __restrict__ ss)
{
    const int bid = blockIdx.x;
    const int t = threadIdx.x;

    if (bid < 1024) {
        int row = bid & 511;
        const float* S = (bid < 512) ? S1 : S2;
        int* h = (bid < 512) ? h1 : h2;
        float* s = (bid < 512) ? s1 : s2;
        const float4* p = (const float4*)(S + (size_t)row * OUT_DIM);
#pragma unroll
        for (int m = 0; m < 8; ++m) {
            int q = t + m * 256;
            float4 v = p[q];
            int base = q * 4;
            if (v.x != 0.f) { h[row] = base + 0; s[row] = v.x; }
            if (v.y != 0.f) { h[row] = base + 1; s[row] = v.y; }
            if (v.z != 0.f) { h[row] = base + 2; s[row] = v.z; }
            if (v.w != 0.f) { h[row] = base + 3; s[row] = v.w; }
        }
        if (bid == 0 && t < B_DIM) ss[t] = 0.f;
        return;
    }

    // pack: one block per (b, rb) = 16 rows of one batch
    const int u = bid - 1024;             // 0..511
    const int b = u >> 5, rb = u & 31;
    __shared__ float xs[16 * HW];         // 12.25 KB, rows contiguous in x
    const float* src = x + ((size_t)b * C_DIM + rb * 16) * HW;
#pragma unroll
    for (int i = 0; i < 13; ++i) {
        int idx = t + i * 256;
        if (idx < 16 * HW) xs[idx] = src[idx];
    }
    __syncthreads();

    const int r = t & 15, u0 = t >> 4;    // r = row-in-block, u0 = k-unit
#pragma unroll
    for (int p = 0; p < 2; ++p) {
        int unit = u0 + p * 16;           // 0..27 (28 units of 8 k)
        if (unit < 28) {
            bf16x8 hv, lv;
#pragma unroll
            for (int e = 0; e < 8; ++e) {
                int k = unit * 8 + e;
                float v = (k < HW) ? xs[r * HW + k] : 0.f;
                unsigned int uv = __float_as_uint(v);
                unsigned short hi = (unsigned short)(uv >> 16);
                float hif = __uint_as_float(((unsigned int)hi) << 16);
                hv[e] = (short)hi;
                lv[e] = (short)(__float_as_uint(v - hif) >> 16);
            }
            int kb = unit >> 2, lk = unit & 3;
            size_t base = ((((size_t)b * 32 + rb) * 7 + kb) * 4 + lk) * 128 + r * 8;
            *(bf16x8*)(PH + base) = hv;
            *(bf16x8*)(PLo + base) = lv;
        }
    }
}

// ---------------------------------------------------------------------------
// K2: Gram via MFMA, fragments loaded DIRECTLY from L2-resident packed layout.
// 256 blocks x 256 thr (4 waves). Block (b, 128x128 tile); wave = 64x64
// quadrant (wr,wc), acc[4][4]. 7 K-chunks of 32, register double-buffered,
// NO barriers in the K-loop. LDS used only for the 8192-bin scatter.
// XCD swizzle: bid&7 = XCD, 2 batches/XCD (packed x ~0.9 MB, L2-resident).
// ---------------------------------------------------------------------------
__global__ __launch_bounds__(256) void gram_mfma(
    const unsigned short* __restrict__ PH, const unsigned short* __restrict__ PLo,
    const int* __restrict__ h1, const float* __restrict__ s1,
    const int* __restrict__ h2, const float* __restrict__ s2,
    float* __restrict__ partials)
{
    __shared__ float bins[OUT_DIM];       // 32 KB

    const int bid = blockIdx.x;
    const int xcd = bid & 7;
    const int idx = bid >> 3;             // 0..31
    const int b   = xcd + 8 * (idx & 1);
    const int tile = idx >> 1;            // 0..15
    const int c1b = (tile >> 2) * 128, c2b = (tile & 3) * 128;

    const int t = threadIdx.x;
    const int l = t & 63, w = t >> 6;
    const int wr = w >> 1, wc = w & 1;    // 2x2 wave grid, 64x64 each

    for (int mm = t; mm < OUT_DIM; mm += 256) bins[mm] = 0.f;

    // fragment base offsets: frag(rb, kb) at ((b*32+rb)*7 + kb)*512 + l*8
    const size_t arb0 = ((size_t)b * 32 + (c1b >> 4) + wr * 4) * 7;  // +m*7
    const size_t brb0 = ((size_t)b * 32 + (c2b >> 4) + wc * 4) * 7;  // +n*7
    const int loff = l * 8;

#define FRAG(P, rbase, m, kb) (*(const bf16x8*)((P) + ((rbase) + (size_t)(m) * 7 + (kb)) * 512 + loff))

    f32x4 acc[4][4];
#pragma unroll
    for (int m = 0; m < 4; ++m)
#pragma unroll
        for (int n = 0; n < 4; ++n) acc[m][n] = (f32x4){0.f, 0.f, 0.f, 0.f};

    bf16x8 ah[2][4], al[2][4], bh[2][4], bl[2][4];
#pragma unroll
    for (int m = 0; m < 4; ++m) {
        ah[0][m] = FRAG(PH,  arb0, m, 0);
        al[0][m] = FRAG(PLo, arb0, m, 0);
        bh[0][m] = FRAG(PH,  brb0, m, 0);
        bl[0][m] = FRAG(PLo, brb0, m, 0);
    }

#pragma unroll
    for (int kb = 0; kb < 7; ++kb) {
        const int cur = kb & 1, nxt = cur ^ 1;
        if (kb < 6) {
#pragma unroll
            for (int m = 0; m < 4; ++m) {
                ah[nxt][m] = FRAG(PH,  arb0, m, kb + 1);
                al[nxt][m] = FRAG(PLo, arb0, m, kb + 1);
                bh[nxt][m] = FRAG(PH,  brb0, m, kb + 1);
                bl[nxt][m] = FRAG(PLo, brb0, m, kb + 1);
            }
        }
#pragma unroll
        for (int m = 0; m < 4; ++m)
#pragma unroll
            for (int n = 0; n < 4; ++n) {
                acc[m][n] = __builtin_amdgcn_mfma_f32_16x16x32_bf16(ah[cur][m], bh[cur][n], acc[m][n], 0, 0, 0);
                acc[m][n] = __builtin_amdgcn_mfma_f32_16x16x32_bf16(ah[cur][m], bl[cur][n], acc[m][n], 0, 0, 0);
                acc[m][n] = __builtin_amdgcn_mfma_f32_16x16x32_bf16(al[cur][m], bh[cur][n], acc[m][n], 0, 0, 0);
            }
    }
#undef FRAG

    // C/D layout (verified R3/R4): c2 = col = lane&15, c1 = row = (lane>>4)*4 + reg
    const int lrow = l & 15, lk = l >> 4;
    int   hh1[4][4]; float sv1[4][4];
    int   hh2[4];    float sv2[4];
#pragma unroll
    for (int m = 0; m < 4; ++m)
#pragma unroll
        for (int r = 0; r < 4; ++r) {
            int c1 = c1b + wr * 64 + m * 16 + lk * 4 + r;
            hh1[m][r] = h1[c1]; sv1[m][r] = s1[c1];
        }
#pragma unroll
    for (int n = 0; n < 4; ++n) {
        int c2 = c2b + wc * 64 + n * 16 + lrow;
        hh2[n] = h2[c2]; sv2[n] = s2[c2];
    }

    __syncthreads();                      // bins zeroed; compute done
#pragma unroll
    for (int m = 0; m < 4; ++m)
#pragma unroll
        for (int n = 0; n < 4; ++n)
#pragma unroll
            for (int r = 0; r < 4; ++r) {
                int bin = (hh1[m][r] + hh2[n]) & (OUT_DIM - 1);
                atomicAdd(&bins[bin], acc[m][n][r] * sv1[m][r] * sv2[n]);
            }
    __syncthreads();

    float* outp = partials + (size_t)(b * 16 + tile) * OUT_DIM;
    for (int mm = t; mm < OUT_DIM; mm += 256) outp[mm] = bins[mm];
}

// ---------------------------------------------------------------------------
// K3a: reduce 16 slabs -> signed-sqrt values into slab 0; per-batch sum-sq.
// ---------------------------------------------------------------------------
__global__ __launch_bounds__(256) void fin_a(
    float* __restrict__ partials, float* __restrict__ ss)
{
    const int b = blockIdx.x >> 4, ch = blockIdx.x & 15, t = threadIdx.x;
    float sq = 0.f;
    float vals[2];
    int ks[2];
#pragma unroll
    for (int i = 0; i < 2; ++i) {
        int k = ch * 512 + i * 256 + t;
        ks[i] = k;
        float a = 0.f;
#pragma unroll
        for (int tile = 0; tile < 16; ++tile)
            a += partials[(size_t)(b * 16 + tile) * OUT_DIM + k];
        a *= (float)OUT_DIM;
        float sg = (a > 0.f) ? 1.f : ((a < 0.f) ? -1.f : 0.f);
        vals[i] = sg * sqrtf(fabsf(a) + 1e-5f);
        sq += fabsf(a) + 1e-5f;          // = vals[i]^2
    }
#pragma unroll
    for (int off = 32; off; off >>= 1) sq += __shfl_down(sq, off, 64);
    __shared__ float red[4];
    if ((t & 63) == 0) red[t >> 6] = sq;
    __syncthreads();
    if (t == 0) atomicAdd(&ss[b], red[0] + red[1] + red[2] + red[3]);
#pragma unroll
    for (int i = 0; i < 2; ++i)
        partials[(size_t)(b * 16) * OUT_DIM + ks[i]] = vals[i];
}

// ---------------------------------------------------------------------------
// K3b: L2 normalize.
// ---------------------------------------------------------------------------
__global__ __launch_bounds__(256) void fin_b(
    const float* __restrict__ partials, const float* __restrict__ ss,
    float* __restrict__ out)
{
    const int b = blockIdx.x >> 4, ch = blockIdx.x & 15, t = threadIdx.x;
    float inv = 1.f / fmaxf(sqrtf(ss[b]), 1e-12f);
#pragma unroll
    for (int i = 0; i < 2; ++i) {
        int k = ch * 512 + i * 256 + t;
        out[(size_t)b * OUT_DIM + k] = partials[(size_t)(b * 16) * OUT_DIM + k] * inv;
    }
}

// ---------------------------------------------------------------------------
extern "C" void kernel_launch(void* const* d_in, const int* in_sizes, int n_in,
                              void* d_out, int out_size, void* d_ws, size_t ws_size,
                              hipStream_t stream) {
    const float* x   = (const float*)d_in[0];
    const float* sk1 = (const float*)d_in[1];
    const float* sk2 = (const float*)d_in[2];

    char* ws = (char*)d_ws;
    int*   h1 = (int*)(ws);                              //       0 + 2048
    float* s1 = (float*)(ws + 2048);                     //    2048 + 2048
    int*   h2 = (int*)(ws + 4096);                       //    4096 + 2048
    float* s2 = (float*)(ws + 6144);                     //    6144 + 2048
    float* ss = (float*)(ws + 8192);                     //    8192 + 256
    float* partials = (float*)(ws + 8448);               // [256][8192] f32 = 8388608
    unsigned short* PH  = (unsigned short*)(ws + 8397056);   // 16*32*7*512 u16 = 7340032 B
    unsigned short* PLo = (unsigned short*)(ws + 15737088);  // + 7340032 = 23077120 total

    prep<<<1536, 256, 0, stream>>>(x, sk1, sk2, h1, s1, h2, s2, PH, PLo, ss);
    gram_mfma<<<256, 256, 0, stream>>>(PH, PLo, h1, s1, h2, s2, partials);
    fin_a<<<256, 256, 0, stream>>>(partials, ss);
    fin_b<<<256, 256, 0, stream>>>(partials, ss, (float*)d_out);
}